// Round 9
// baseline (937.742 us; speedup 1.0000x reference)
//
#include <hip/hip_runtime.h>
#include <hip/hip_fp16.h>
#include <math.h>

#define ND 64
constexpr int BKT_SHIFT = 9;          // 512 nodes per bucket; NBK = ceil(100k/512) = 196 <= 256
constexpr int BKT_MASK = (1 << BKT_SHIFT) - 1;
constexpr int BCUR_PAD = 16;          // ints -> 64 B per cursor
constexpr int STG_TILE = 8192;        // edges per stage block

__device__ __forceinline__ float sigmoidf_(float x){ return 1.f/(1.f+__expf(-x)); }
__device__ __forceinline__ __half2 h2lo(uint2 v){ return *reinterpret_cast<__half2*>(&v.x); }
__device__ __forceinline__ __half2 h2hi(uint2 v){ return *reinterpret_cast<__half2*>(&v.y); }
__device__ __forceinline__ __half2 shxor_h2(__half2 h, int off){
  unsigned u = *reinterpret_cast<unsigned*>(&h);
  u = __shfl_xor(u, off, 64);
  return *reinterpret_cast<__half2*>(&u);
}

// ---------------- bucket-hierarchical CSR build ----------------
__global__ void k_bhist(const int* __restrict__ col, int* __restrict__ bgcnt,
                        int E, int NBK){
  __shared__ int lhist[512];
  int t0 = blockIdx.x * STG_TILE;
  int t1 = t0 + STG_TILE; if (t1 > E) t1 = E;
  for (int i = threadIdx.x; i < NBK; i += 256) lhist[i] = 0;
  __syncthreads();
  for (int i = t0 + threadIdx.x; i < t1; i += 256)
    atomicAdd(&lhist[col[i] >> BKT_SHIFT], 1);
  __syncthreads();
  for (int i = threadIdx.x; i < NBK; i += 256)
    if (lhist[i] > 0) atomicAdd(&bgcnt[i], lhist[i]);
}

__global__ void k_bscan(const int* __restrict__ bgcnt, int* __restrict__ bstart,
                        int* __restrict__ rowptr, int NBK, int E, int N){
  __shared__ int tmp[256];
  int t = threadIdx.x;
  int v = (t < NBK) ? bgcnt[t] : 0;
  tmp[t] = v; __syncthreads();
  for (int off=1; off<256; off<<=1){
    int u = (t>=off) ? tmp[t-off] : 0;
    __syncthreads();
    tmp[t] += u;
    __syncthreads();
  }
  if (t <= NBK) bstart[t] = (t==0) ? 0 : tmp[t-1];
  if (t == 0) rowptr[N] = E;
}

__global__ void k_bcinit(const int* __restrict__ bstart, int* __restrict__ bcur, int NBK){
  int b = blockIdx.x*blockDim.x + threadIdx.x;
  if (b < NBK) bcur[b*BCUR_PAD] = bstart[b];
}

__global__ void k_stage2(const int* __restrict__ row, const int* __restrict__ col,
                         int* __restrict__ bcur, unsigned* __restrict__ pairs,
                         int E, int NBK){
  __shared__ int lhist[512];
  __shared__ int lbase[512];
  int t0 = blockIdx.x * STG_TILE;
  int t1 = t0 + STG_TILE; if (t1 > E) t1 = E;
  for (int i = threadIdx.x; i < NBK; i += 256) lhist[i] = 0;
  __syncthreads();
  for (int i = t0 + threadIdx.x; i < t1; i += 256)
    atomicAdd(&lhist[col[i] >> BKT_SHIFT], 1);
  __syncthreads();
  for (int i = threadIdx.x; i < NBK; i += 256){
    int c = lhist[i];
    lbase[i] = (c > 0) ? atomicAdd(&bcur[i*BCUR_PAD], c) : 0;
    lhist[i] = 0;
  }
  __syncthreads();
  for (int i = t0 + threadIdx.x; i < t1; i += 256){
    int d = col[i];
    int b = d >> BKT_SHIFT;
    int pos = lbase[b] + atomicAdd(&lhist[b], 1);
    pairs[pos] = ((unsigned)row[i] << BKT_SHIFT) | (unsigned)(d & BKT_MASK);
  }
}

__global__ void k_place(const unsigned* __restrict__ pairs, const int* __restrict__ bstart,
                        int* __restrict__ rowptr, float* __restrict__ dinv,
                        int* __restrict__ csr, int N){
  __shared__ int h[1 << BKT_SHIFT];
  __shared__ int excl[1 << BKT_SHIFT];
  __shared__ int tsum[256];
  int b = blockIdx.x;
  int base = b << BKT_SHIFT;
  int nend = base + (1 << BKT_SHIFT); if (nend > N) nend = N;
  int cnt = nend - base;
  int t = threadIdx.x;
  int s = bstart[b], e = bstart[b+1];

  h[2*t] = 0; h[2*t+1] = 0;
  __syncthreads();
  for (int i = s + t; i < e; i += 256)
    atomicAdd(&h[pairs[i] & BKT_MASK], 1);
  __syncthreads();
  int a0 = h[2*t], a1 = h[2*t+1];
  tsum[t] = a0 + a1;
  __syncthreads();
  for (int off=1; off<256; off<<=1){
    int u = (t>=off) ? tsum[t-off] : 0;
    __syncthreads();
    tsum[t] += u;
    __syncthreads();
  }
  int base0 = (t==0) ? 0 : tsum[t-1];
  excl[2*t]   = base0;
  excl[2*t+1] = base0 + a0;
  __syncthreads();
  for (int c = t; c < cnt; c += 256){
    int deg = h[c];
    rowptr[base + c] = s + excl[c];
    dinv[base + c] = rsqrtf((float)(deg + 1));   // +1 = self loop
  }
  __syncthreads();
  for (int c = t; c < cnt; c += 256) h[c] = s + excl[c];
  __syncthreads();
  for (int i = s + t; i < e; i += 256){
    unsigned p = pairs[i];
    int pos = atomicAdd(&h[p & BKT_MASK], 1);
    csr[pos] = (int)(p >> BKT_SHIFT);
  }
}

// ---------------- input MLP: s0 = fp16( dinv * relu(x @ W0 + b0) ) ----------------
__global__ void k_input(const float* __restrict__ x, const float* __restrict__ W0,
                        const float* __restrict__ b0, const float* __restrict__ dinv,
                        __half* __restrict__ s, int N){
  __shared__ float w0s[15*ND];
  __shared__ float b0s[ND];
  int tid = threadIdx.x;
  for (int i=tid; i<15*ND; i+=256) w0s[i] = W0[i];
  if (tid < ND) b0s[tid] = b0[tid];
  __syncthreads();
  int node = blockIdx.x*4 + (tid>>6);
  int f = tid & 63;
  if (node < N){
    float acc = b0s[f];
    const float* xr = x + (size_t)node*15;
    #pragma unroll
    for (int k=0;k<15;k++) acc += xr[k]*w0s[k*ND+f];
    s[(size_t)node*ND+f] = __float2half_rn(dinv[node]*fmaxf(acc, 0.f));
  }
}

// ---------------- fused propagation step, packed-fp16 gather ----------------
__global__ void k_prop(const __half* __restrict__ sbuf, const int* __restrict__ rowptr,
                       const int* __restrict__ csr, const float* __restrict__ dinv,
                       const float* __restrict__ Wc, const float* __restrict__ bc,
                       __half* __restrict__ s_new, __half* __restrict__ outh,
                       int N, int wout){
  __shared__ float wcs[ND*ND];
  __shared__ float xs[16][ND];
  __shared__ float bcs[ND];
  const uint2* g8 = (const uint2*)sbuf;
  int tid = threadIdx.x;
  for (int i=tid; i<ND*ND; i+=256) wcs[i] = Wc[i];
  if (tid < ND) bcs[tid] = bc[tid];
  int nb = blockIdx.x*16;
  int wv = tid>>6, lane = tid&63;
  int grp = lane>>4, li = lane&15;

  for (int q=0; q<4; ++q){
    int node = nb + wv*4 + q;
    float val = 0.f;
    if (node < N){
      int s = rowptr[node], e = rowptr[node+1];
      __half2 z = __float2half2_rn(0.f);
      __half2 a0x=z,a0y=z, a1x=z,a1y=z, a2x=z,a2y=z, a3x=z,a3y=z;
      int i = s;
      for (; i + 16 <= e; i += 16){
        int s0 = csr[i +  0 + grp];
        int s1 = csr[i +  4 + grp];
        int s2 = csr[i +  8 + grp];
        int s3 = csr[i + 12 + grp];
        uint2 v0 = g8[(size_t)s0*16 + li];
        uint2 v1 = g8[(size_t)s1*16 + li];
        uint2 v2 = g8[(size_t)s2*16 + li];
        uint2 v3 = g8[(size_t)s3*16 + li];
        a0x = __hadd2(a0x, h2lo(v0)); a0y = __hadd2(a0y, h2hi(v0));
        a1x = __hadd2(a1x, h2lo(v1)); a1y = __hadd2(a1y, h2hi(v1));
        a2x = __hadd2(a2x, h2lo(v2)); a2y = __hadd2(a2y, h2hi(v2));
        a3x = __hadd2(a3x, h2lo(v3)); a3y = __hadd2(a3y, h2hi(v3));
      }
      for (; i + 4 <= e; i += 4){
        int s0 = csr[i + grp];
        uint2 v0 = g8[(size_t)s0*16 + li];
        a0x = __hadd2(a0x, h2lo(v0)); a0y = __hadd2(a0y, h2hi(v0));
      }
      int r = e - i;
      if (grp < r){
        int s0 = csr[i + grp];
        uint2 v0 = g8[(size_t)s0*16 + li];
        a1x = __hadd2(a1x, h2lo(v0)); a1y = __hadd2(a1y, h2hi(v0));
      }
      __half2 sxh = __hadd2(__hadd2(a0x,a1x), __hadd2(a2x,a3x));
      __half2 syh = __hadd2(__hadd2(a0y,a1y), __hadd2(a2y,a3y));
      sxh = __hadd2(sxh, shxor_h2(sxh, 16));
      syh = __hadd2(syh, shxor_h2(syh, 16));
      sxh = __hadd2(sxh, shxor_h2(sxh, 32));
      syh = __hadd2(syh, shxor_h2(syh, 32));
      uint2 sv = g8[(size_t)node*16 + li];        // self loop
      sxh = __hadd2(sxh, h2lo(sv));
      syh = __hadd2(syh, h2hi(sv));
      val = (grp==0) ? __half2float(__low2half(sxh))
          : (grp==1) ? __half2float(__high2half(sxh))
          : (grp==2) ? __half2float(__low2half(syh))
          :            __half2float(__high2half(syh));
    }
    xs[wv*4+q][4*li+grp] = val;
  }
  __syncthreads();

  int f = tid&63, nq = tid>>6;
  float acc0=0.f, acc1=0.f, acc2=0.f, acc3=0.f;
  #pragma unroll 16
  for (int k=0;k<ND;k++){
    float w = wcs[k*ND+f];
    acc0 += w*xs[nq*4+0][k];
    acc1 += w*xs[nq*4+1][k];
    acc2 += w*xs[nq*4+2][k];
    acc3 += w*xs[nq*4+3][k];
  }
  int n0 = nb + nq*4;
  float bcf = bcs[f];
  #pragma unroll
  for (int j=0; j<4; ++j){
    int node = n0 + j;
    if (node < N){
      float a = (j==0)?acc0:(j==1)?acc1:(j==2)?acc2:acc3;
      float dn = dinv[node];
      float r = fmaxf(dn*a + bcf, 0.f);
      if (wout) outh[(size_t)node*ND+f] = __float2half_rn(r);        // last step: relu-out only
      else      s_new[(size_t)node*ND+f] = __float2half_rn(dn*r);    // intermediate: pre-scaled
    }
  }
}

// ---------------- per-graph contiguous ranges (batch is sorted) ----------------
__global__ void k_goff(const int* __restrict__ batch, int* __restrict__ goff, int N, int B){
  int i = blockIdx.x*blockDim.x + threadIdx.x;
  if (i >= N) return;
  int b = batch[i];
  if (i == 0){ for (int g2=0; g2<=b; ++g2) goff[g2]=0; }
  else {
    int bp = batch[i-1];
    for (int g2=bp+1; g2<=b; ++g2) goff[g2]=i;
  }
  if (i == N-1){ for (int g2=b+1; g2<=B; ++g2) goff[g2]=N; }
}

// ---------------- fused Set2Set: 6 steps of LSTM + attention, then final MLP ----------------
// Per-graph recurrence is independent -> no global sync needed. 2 graphs per block:
// waves 0,1 -> graph g0; waves 2,3 -> graph g0+1. State (q_star,h,c) lives in LDS.
__global__ void k_s2s(const __half* __restrict__ nodef, const int* __restrict__ goff,
                      const float* __restrict__ Wih, const float* __restrict__ Whh,
                      const float* __restrict__ bih, const float* __restrict__ bhh,
                      const float* __restrict__ W1, const float* __restrict__ b1,
                      const float* __restrict__ W2, const float* __restrict__ b2,
                      float* __restrict__ outy, int B){
  __shared__ float qsr[2][128];
  __shared__ float hlr[2][64];
  __shared__ float clr[2][64];
  __shared__ float gat[2][256];
  __shared__ float redm[2][2], redd[2][2];
  __shared__ float redr[2][2][64];
  __shared__ float yy[2][64];
  int tid = threadIdx.x;
  int g0 = blockIdx.x*2;
  if (g0 >= B) return;
  for (int i=tid;i<2*128;i+=256) qsr[i>>7][i&127]=0.f;
  if (tid<128){ hlr[tid>>6][tid&63]=0.f; clr[tid>>6][tid&63]=0.f; }
  __syncthreads();
  int lane=tid&63, wv=tid>>6;
  int gg_w = wv>>1, wp = wv&1;   // graph-of-wave, sub-wave index
  for (int step=0; step<6; ++step){
    // LSTM gates: thread = gate index j, 2 graphs at once
    float bb = bih[tid]+bhh[tid];
    float a0=bb, a1=bb;
    const float* wr = Wih + (size_t)tid*128;
    for (int k=0;k<128;k++){ float w=wr[k]; a0+=w*qsr[0][k]; a1+=w*qsr[1][k]; }
    const float* wr2 = Whh + (size_t)tid*64;
    for (int k=0;k<64;k++){ float w=wr2[k]; a0+=w*hlr[0][k]; a1+=w*hlr[1][k]; }
    gat[0][tid]=a0; gat[1][tid]=a1;
    __syncthreads();
    if (tid<128){
      int gg=tid>>6, d=tid&63;
      float ig=sigmoidf_(gat[gg][d]);
      float fg=sigmoidf_(gat[gg][64+d]);
      float gv=tanhf(gat[gg][128+d]);
      float og=sigmoidf_(gat[gg][192+d]);
      float c = fg*clr[gg][d]+ig*gv;
      float h = og*tanhf(c);
      clr[gg][d]=c; hlr[gg][d]=h; qsr[gg][d]=h;
    }
    __syncthreads();
    // attention (online softmax), 2 waves per graph
    {
      int g = g0+gg_w;
      int s = goff[g], e = goff[g+1];
      float q = hlr[gg_w][lane];
      float m=-3.0e38f, denom=0.f, racc=0.f;
      for (int n=s+wp; n<e; n+=2){
        float v = __half2float(nodef[(size_t)n*64+lane]);
        float p = v*q;
        #pragma unroll
        for (int off=32; off>=1; off>>=1) p += __shfl_xor(p, off, 64);
        if (p>m){ float sc=__expf(m-p); denom*=sc; racc*=sc; m=p; }
        float w=__expf(p-m);
        denom+=w; racc+=w*v;
      }
      if (lane==0){ redm[gg_w][wp]=m; redd[gg_w][wp]=denom; }
      redr[gg_w][wp][lane]=racc;
    }
    __syncthreads();
    if (wp==0){   // waves 0 and 2 finalize their graph's r
      float m0=redm[gg_w][0], m1=redm[gg_w][1];
      float mm=fmaxf(m0,m1);
      float s0=__expf(m0-mm), s1=__expf(m1-mm);
      float dt=redd[gg_w][0]*s0+redd[gg_w][1]*s1;
      float rs=redr[gg_w][0][lane]*s0+redr[gg_w][1][lane]*s1;
      qsr[gg_w][64+lane] = (dt>0.f)? rs/dt : 0.f;
    }
    __syncthreads();
  }
  // final MLP
  if (tid<128){
    int gg=tid>>6, f=tid&63;
    float acc=b1[f];
    for (int k=0;k<128;k++) acc += qsr[gg][k]*W1[k*64+f];
    yy[gg][f]=fmaxf(acc,0.f);
  }
  __syncthreads();
  if (tid<24){
    int gg=tid/12, o=tid%12;
    float a2=b2[o];
    for (int k=0;k<64;k++) a2 += yy[gg][k]*W2[k*12+o];
    outy[(size_t)(g0+gg)*12+o]=a2;
  }
}

extern "C" void kernel_launch(void* const* d_in, const int* in_sizes, int n_in,
                              void* d_out, int out_size, void* d_ws, size_t ws_size,
                              hipStream_t stream){
  const float* x    = (const float*)d_in[0];
  const int*   ei   = (const int*)d_in[1];
  const int*   batch= (const int*)d_in[2];
  const float* W0   = (const float*)d_in[3];
  const float* b0   = (const float*)d_in[4];
  const float* Wc   = (const float*)d_in[5];
  const float* bc   = (const float*)d_in[6];
  const float* Wih  = (const float*)d_in[7];
  const float* Whh  = (const float*)d_in[8];
  const float* bih  = (const float*)d_in[9];
  const float* bhh  = (const float*)d_in[10];
  const float* W1   = (const float*)d_in[11];
  const float* b1   = (const float*)d_in[12];
  const float* W2   = (const float*)d_in[13];
  const float* b2   = (const float*)d_in[14];
  float* yout = (float*)d_out;

  const int N = in_sizes[0]/15;
  const int E = in_sizes[1]/2;
  const int B = out_size/12;
  const int NBK = (N + (1<<BKT_SHIFT) - 1) >> BKT_SHIFT;
  const int* row = ei;
  const int* col = ei + E;

  char* ws = (char*)d_ws;
  size_t off = 0;
  auto alloc = [&](size_t bytes)->void*{
    void* p = ws + off; off = (off + bytes + 255) & ~(size_t)255; return p;
  };
  int*      bgcnt   = (int*)     alloc((size_t)(NBK+1)*4);
  int*      bstart  = (int*)     alloc((size_t)(NBK+1)*4);
  int*      bcur    = (int*)     alloc((size_t)NBK*BCUR_PAD*4);
  int*      rowptr  = (int*)     alloc((size_t)(N+1)*4);
  unsigned* pairs   = (unsigned*)alloc((size_t)E*4);
  int*      csr     = (int*)     alloc((size_t)E*4);
  float*    dinv    = (float*)   alloc((size_t)N*4);
  __half*   nodef   = (__half*)  alloc((size_t)N*ND*2);
  __half*   s_a     = (__half*)  alloc((size_t)N*ND*2);
  __half*   s_b     = (__half*)  alloc((size_t)N*ND*2);
  int*      goff    = (int*)     alloc((size_t)(B+1)*4);
  (void)ws_size; (void)n_in;

  hipMemsetAsync(bgcnt, 0, (size_t)(NBK+1)*4, stream);

  int nstg = (E + STG_TILE - 1)/STG_TILE;
  k_bhist <<<nstg, 256, 0, stream>>>(col, bgcnt, E, NBK);
  k_bscan <<<1, 256, 0, stream>>>(bgcnt, bstart, rowptr, NBK, E, N);
  k_bcinit<<<(NBK+255)/256, 256, 0, stream>>>(bstart, bcur, NBK);
  k_stage2<<<nstg, 256, 0, stream>>>(row, col, bcur, pairs, E, NBK);
  k_place <<<NBK, 256, 0, stream>>>(pairs, bstart, rowptr, dinv, csr, N);

  k_input<<<(N+3)/4, 256, 0, stream>>>(x, W0, b0, dinv, s_a, N);
  __half* scur = s_a; __half* snxt = s_b;
  for (int s6=0; s6<6; ++s6){
    k_prop<<<(N+15)/16, 256, 0, stream>>>(scur, rowptr, csr, dinv,
                                          Wc, bc, snxt, nodef, N, (s6==5)?1:0);
    __half* t = scur; scur = snxt; snxt = t;
  }

  k_goff<<<(N+255)/256, 256, 0, stream>>>(batch, goff, N, B);
  k_s2s<<<(B+1)/2, 256, 0, stream>>>(nodef, goff, Wih, Whh, bih, bhh,
                                     W1, b1, W2, b2, yout, B);
}

// Round 10
// 868.456 us; speedup vs baseline: 1.0798x; 1.0798x over previous
//
#include <hip/hip_runtime.h>
#include <hip/hip_fp16.h>
#include <math.h>

#define ND 64
constexpr int BKT_SHIFT = 9;          // 512 nodes per bucket; NBK = ceil(100k/512) = 196 <= 256
constexpr int BKT_MASK = (1 << BKT_SHIFT) - 1;
constexpr int BCUR_PAD = 16;          // ints -> 64 B per cursor
constexpr int STG_TILE = 8192;        // edges per stage block

__device__ __forceinline__ float sigmoidf_(float x){ return 1.f/(1.f+__expf(-x)); }
__device__ __forceinline__ __half2 h2lo(uint2 v){ return *reinterpret_cast<__half2*>(&v.x); }
__device__ __forceinline__ __half2 h2hi(uint2 v){ return *reinterpret_cast<__half2*>(&v.y); }
__device__ __forceinline__ __half2 shxor_h2(__half2 h, int off){
  unsigned u = *reinterpret_cast<unsigned*>(&h);
  u = __shfl_xor(u, off, 64);
  return *reinterpret_cast<__half2*>(&u);
}

// ---------------- bucket-hierarchical CSR build ----------------
__global__ void k_bhist(const int* __restrict__ col, int* __restrict__ bgcnt,
                        int E, int NBK){
  __shared__ int lhist[512];
  int t0 = blockIdx.x * STG_TILE;
  int t1 = t0 + STG_TILE; if (t1 > E) t1 = E;
  for (int i = threadIdx.x; i < NBK; i += 256) lhist[i] = 0;
  __syncthreads();
  for (int i = t0 + threadIdx.x; i < t1; i += 256)
    atomicAdd(&lhist[col[i] >> BKT_SHIFT], 1);
  __syncthreads();
  for (int i = threadIdx.x; i < NBK; i += 256)
    if (lhist[i] > 0) atomicAdd(&bgcnt[i], lhist[i]);
}

__global__ void k_bscan(const int* __restrict__ bgcnt, int* __restrict__ bstart,
                        int* __restrict__ rowptr, int NBK, int E, int N){
  __shared__ int tmp[256];
  int t = threadIdx.x;
  int v = (t < NBK) ? bgcnt[t] : 0;
  tmp[t] = v; __syncthreads();
  for (int off=1; off<256; off<<=1){
    int u = (t>=off) ? tmp[t-off] : 0;
    __syncthreads();
    tmp[t] += u;
    __syncthreads();
  }
  if (t <= NBK) bstart[t] = (t==0) ? 0 : tmp[t-1];
  if (t == 0) rowptr[N] = E;
}

__global__ void k_bcinit(const int* __restrict__ bstart, int* __restrict__ bcur, int NBK){
  int b = blockIdx.x*blockDim.x + threadIdx.x;
  if (b < NBK) bcur[b*BCUR_PAD] = bstart[b];
}

__global__ void k_stage2(const int* __restrict__ row, const int* __restrict__ col,
                         int* __restrict__ bcur, unsigned* __restrict__ pairs,
                         int E, int NBK){
  __shared__ int lhist[512];
  __shared__ int lbase[512];
  int t0 = blockIdx.x * STG_TILE;
  int t1 = t0 + STG_TILE; if (t1 > E) t1 = E;
  for (int i = threadIdx.x; i < NBK; i += 256) lhist[i] = 0;
  __syncthreads();
  for (int i = t0 + threadIdx.x; i < t1; i += 256)
    atomicAdd(&lhist[col[i] >> BKT_SHIFT], 1);
  __syncthreads();
  for (int i = threadIdx.x; i < NBK; i += 256){
    int c = lhist[i];
    lbase[i] = (c > 0) ? atomicAdd(&bcur[i*BCUR_PAD], c) : 0;
    lhist[i] = 0;
  }
  __syncthreads();
  for (int i = t0 + threadIdx.x; i < t1; i += 256){
    int d = col[i];
    int b = d >> BKT_SHIFT;
    int pos = lbase[b] + atomicAdd(&lhist[b], 1);
    pairs[pos] = ((unsigned)row[i] << BKT_SHIFT) | (unsigned)(d & BKT_MASK);
  }
}

__global__ void k_place(const unsigned* __restrict__ pairs, const int* __restrict__ bstart,
                        int* __restrict__ rowptr, float* __restrict__ dinv,
                        int* __restrict__ csr, int N){
  __shared__ int h[1 << BKT_SHIFT];
  __shared__ int excl[1 << BKT_SHIFT];
  __shared__ int tsum[256];
  int b = blockIdx.x;
  int base = b << BKT_SHIFT;
  int nend = base + (1 << BKT_SHIFT); if (nend > N) nend = N;
  int cnt = nend - base;
  int t = threadIdx.x;
  int s = bstart[b], e = bstart[b+1];

  h[2*t] = 0; h[2*t+1] = 0;
  __syncthreads();
  for (int i = s + t; i < e; i += 256)
    atomicAdd(&h[pairs[i] & BKT_MASK], 1);
  __syncthreads();
  int a0 = h[2*t], a1 = h[2*t+1];
  tsum[t] = a0 + a1;
  __syncthreads();
  for (int off=1; off<256; off<<=1){
    int u = (t>=off) ? tsum[t-off] : 0;
    __syncthreads();
    tsum[t] += u;
    __syncthreads();
  }
  int base0 = (t==0) ? 0 : tsum[t-1];
  excl[2*t]   = base0;
  excl[2*t+1] = base0 + a0;
  __syncthreads();
  for (int c = t; c < cnt; c += 256){
    int deg = h[c];
    rowptr[base + c] = s + excl[c];
    dinv[base + c] = rsqrtf((float)(deg + 1));   // +1 = self loop
  }
  __syncthreads();
  for (int c = t; c < cnt; c += 256) h[c] = s + excl[c];
  __syncthreads();
  for (int i = s + t; i < e; i += 256){
    unsigned p = pairs[i];
    int pos = atomicAdd(&h[p & BKT_MASK], 1);
    csr[pos] = (int)(p >> BKT_SHIFT);
  }
}

// ---------------- input MLP: s0 = fp16( dinv * relu(x @ W0 + b0) ) ----------------
__global__ void k_input(const float* __restrict__ x, const float* __restrict__ W0,
                        const float* __restrict__ b0, const float* __restrict__ dinv,
                        __half* __restrict__ s, int N){
  __shared__ float w0s[15*ND];
  __shared__ float b0s[ND];
  int tid = threadIdx.x;
  for (int i=tid; i<15*ND; i+=256) w0s[i] = W0[i];
  if (tid < ND) b0s[tid] = b0[tid];
  __syncthreads();
  int node = blockIdx.x*4 + (tid>>6);
  int f = tid & 63;
  if (node < N){
    float acc = b0s[f];
    const float* xr = x + (size_t)node*15;
    #pragma unroll
    for (int k=0;k<15;k++) acc += xr[k]*w0s[k*ND+f];
    s[(size_t)node*ND+f] = __float2half_rn(dinv[node]*fmaxf(acc, 0.f));
  }
}

// ---------------- fused propagation step, packed-fp16 gather ----------------
__global__ void k_prop(const __half* __restrict__ sbuf, const int* __restrict__ rowptr,
                       const int* __restrict__ csr, const float* __restrict__ dinv,
                       const float* __restrict__ Wc, const float* __restrict__ bc,
                       __half* __restrict__ s_new, __half* __restrict__ outh,
                       int N, int wout){
  __shared__ float wcs[ND*ND];
  __shared__ float xs[16][ND];
  __shared__ float bcs[ND];
  const uint2* g8 = (const uint2*)sbuf;
  int tid = threadIdx.x;
  for (int i=tid; i<ND*ND; i+=256) wcs[i] = Wc[i];
  if (tid < ND) bcs[tid] = bc[tid];
  int nb = blockIdx.x*16;
  int wv = tid>>6, lane = tid&63;
  int grp = lane>>4, li = lane&15;

  for (int q=0; q<4; ++q){
    int node = nb + wv*4 + q;
    float val = 0.f;
    if (node < N){
      int s = rowptr[node], e = rowptr[node+1];
      __half2 z = __float2half2_rn(0.f);
      __half2 a0x=z,a0y=z, a1x=z,a1y=z, a2x=z,a2y=z, a3x=z,a3y=z;
      int i = s;
      for (; i + 16 <= e; i += 16){
        int s0 = csr[i +  0 + grp];
        int s1 = csr[i +  4 + grp];
        int s2 = csr[i +  8 + grp];
        int s3 = csr[i + 12 + grp];
        uint2 v0 = g8[(size_t)s0*16 + li];
        uint2 v1 = g8[(size_t)s1*16 + li];
        uint2 v2 = g8[(size_t)s2*16 + li];
        uint2 v3 = g8[(size_t)s3*16 + li];
        a0x = __hadd2(a0x, h2lo(v0)); a0y = __hadd2(a0y, h2hi(v0));
        a1x = __hadd2(a1x, h2lo(v1)); a1y = __hadd2(a1y, h2hi(v1));
        a2x = __hadd2(a2x, h2lo(v2)); a2y = __hadd2(a2y, h2hi(v2));
        a3x = __hadd2(a3x, h2lo(v3)); a3y = __hadd2(a3y, h2hi(v3));
      }
      for (; i + 4 <= e; i += 4){
        int s0 = csr[i + grp];
        uint2 v0 = g8[(size_t)s0*16 + li];
        a0x = __hadd2(a0x, h2lo(v0)); a0y = __hadd2(a0y, h2hi(v0));
      }
      int r = e - i;
      if (grp < r){
        int s0 = csr[i + grp];
        uint2 v0 = g8[(size_t)s0*16 + li];
        a1x = __hadd2(a1x, h2lo(v0)); a1y = __hadd2(a1y, h2hi(v0));
      }
      __half2 sxh = __hadd2(__hadd2(a0x,a1x), __hadd2(a2x,a3x));
      __half2 syh = __hadd2(__hadd2(a0y,a1y), __hadd2(a2y,a3y));
      sxh = __hadd2(sxh, shxor_h2(sxh, 16));
      syh = __hadd2(syh, shxor_h2(syh, 16));
      sxh = __hadd2(sxh, shxor_h2(sxh, 32));
      syh = __hadd2(syh, shxor_h2(syh, 32));
      uint2 sv = g8[(size_t)node*16 + li];        // self loop
      sxh = __hadd2(sxh, h2lo(sv));
      syh = __hadd2(syh, h2hi(sv));
      val = (grp==0) ? __half2float(__low2half(sxh))
          : (grp==1) ? __half2float(__high2half(sxh))
          : (grp==2) ? __half2float(__low2half(syh))
          :            __half2float(__high2half(syh));
    }
    xs[wv*4+q][4*li+grp] = val;
  }
  __syncthreads();

  int f = tid&63, nq = tid>>6;
  float acc0=0.f, acc1=0.f, acc2=0.f, acc3=0.f;
  #pragma unroll 16
  for (int k=0;k<ND;k++){
    float w = wcs[k*ND+f];
    acc0 += w*xs[nq*4+0][k];
    acc1 += w*xs[nq*4+1][k];
    acc2 += w*xs[nq*4+2][k];
    acc3 += w*xs[nq*4+3][k];
  }
  int n0 = nb + nq*4;
  float bcf = bcs[f];
  #pragma unroll
  for (int j=0; j<4; ++j){
    int node = n0 + j;
    if (node < N){
      float a = (j==0)?acc0:(j==1)?acc1:(j==2)?acc2:acc3;
      float dn = dinv[node];
      float r = fmaxf(dn*a + bcf, 0.f);
      if (wout) outh[(size_t)node*ND+f] = __float2half_rn(r);        // last step: relu-out only
      else      s_new[(size_t)node*ND+f] = __float2half_rn(dn*r);    // intermediate: pre-scaled
    }
  }
}

// ---------------- per-graph contiguous ranges (batch is sorted) ----------------
__global__ void k_goff(const int* __restrict__ batch, int* __restrict__ goff, int N, int B){
  int i = blockIdx.x*blockDim.x + threadIdx.x;
  if (i >= N) return;
  int b = batch[i];
  if (i == 0){ for (int g2=0; g2<=b; ++g2) goff[g2]=0; }
  else {
    int bp = batch[i-1];
    for (int g2=bp+1; g2<=b; ++g2) goff[g2]=i;
  }
  if (i == N-1){ for (int g2=b+1; g2<=B; ++g2) goff[g2]=N; }
}

// ---------------- LSTM weight prep ----------------
// q == h always, so gates = h@(Wih[:,:64]+Whh)^T + r@Wih[:,64:]^T + (bih+bhh).
// Store transposed [k][j] so the gate loop reads weights coalesced.
__global__ void k_wprep(const float* __restrict__ Wih, const float* __restrict__ Whh,
                        const float* __restrict__ bih, const float* __restrict__ bhh,
                        float* __restrict__ WcombT, float* __restrict__ WrT,
                        float* __restrict__ bsum){
  int k = blockIdx.x;        // 0..63
  int j = threadIdx.x;       // 0..255
  WcombT[k*256 + j] = Wih[(size_t)j*128 + k] + Whh[(size_t)j*64 + k];
  WrT  [k*256 + j] = Wih[(size_t)j*128 + 64 + k];
  if (k == 0) bsum[j] = bih[j] + bhh[j];
}

// ---------------- fused Set2Set: one graph per block, 16 nodes in flight ----------------
// Attention: wave = 4 groups x 16 lanes; group owns a node; lane li holds
// features 4li..4li+3 (uint2). Dot = 4 fma + 4-level 16-lane shuffle. Online
// softmax per group; 16 groups combined via LDS at the end of each step.
__global__ void k_s2s(const __half* __restrict__ nodef, const int* __restrict__ goff,
                      const float* __restrict__ WcombT, const float* __restrict__ WrT,
                      const float* __restrict__ bsum,
                      const float* __restrict__ W1, const float* __restrict__ b1,
                      const float* __restrict__ W2, const float* __restrict__ b2,
                      float* __restrict__ outy, int B){
  __shared__ float qsr[128];        // [h | r] = q_star
  __shared__ float clr[64];
  __shared__ float gat[256];
  __shared__ float redm[16], redd[16];
  __shared__ float redr[16][64];
  __shared__ float yy[64];
  int tid = threadIdx.x;
  int g = blockIdx.x;
  if (g >= B) return;
  if (tid < 128) qsr[tid] = 0.f;
  if (tid < 64)  clr[tid] = 0.f;
  __syncthreads();
  int lane = tid&63, wv = tid>>6;
  int grp = lane>>4, li = lane&15;
  int gidx = wv*4 + grp;
  int s = goff[g], e = goff[g+1];
  const uint2* nf = (const uint2*)nodef;

  for (int step=0; step<6; ++step){
    // ---- LSTM gates: thread = gate j; 128 MACs (combined weights), coalesced
    {
      float a0 = bsum[tid], a1 = 0.f;
      for (int k=0; k<64; k+=2){
        a0 += WcombT[(k  )*256+tid]*qsr[k  ] + WrT[(k  )*256+tid]*qsr[64+k  ];
        a1 += WcombT[(k+1)*256+tid]*qsr[k+1] + WrT[(k+1)*256+tid]*qsr[64+k+1];
      }
      gat[tid] = a0 + a1;
    }
    __syncthreads();
    if (tid < 64){
      float ig = sigmoidf_(gat[tid]);
      float fg = sigmoidf_(gat[64+tid]);
      float gv = tanhf(gat[128+tid]);
      float og = sigmoidf_(gat[192+tid]);
      float c = fg*clr[tid] + ig*gv;
      float h = og*tanhf(c);
      clr[tid] = c;
      qsr[tid] = h;                 // q part of q_star
    }
    __syncthreads();
    // ---- attention, online softmax, 16 nodes in flight
    {
      float4 q4 = *(const float4*)&qsr[4*li];
      float m = -3.0e38f, denom = 0.f;
      float r0=0.f, r1=0.f, r2=0.f, r3=0.f;
      for (int n = s + gidx; n < e; n += 16){
        uint2 v = nf[(size_t)n*16 + li];
        float2 flo = __half22float2(h2lo(v));
        float2 fhi = __half22float2(h2hi(v));
        float p = flo.x*q4.x + flo.y*q4.y + fhi.x*q4.z + fhi.y*q4.w;
        p += __shfl_xor(p, 1, 64);
        p += __shfl_xor(p, 2, 64);
        p += __shfl_xor(p, 4, 64);
        p += __shfl_xor(p, 8, 64);
        if (p > m){                 // group-uniform branch
          float sc = __expf(m - p);
          denom *= sc; r0 *= sc; r1 *= sc; r2 *= sc; r3 *= sc;
          m = p;
        }
        float w = __expf(p - m);
        denom += w;
        r0 += w*flo.x; r1 += w*flo.y; r2 += w*fhi.x; r3 += w*fhi.y;
      }
      if (li == 0){ redm[gidx] = m; redd[gidx] = denom; }
      redr[gidx][4*li+0] = r0;
      redr[gidx][4*li+1] = r1;
      redr[gidx][4*li+2] = r2;
      redr[gidx][4*li+3] = r3;
    }
    __syncthreads();
    if (tid < 64){
      float mm = -3.0e38f;
      #pragma unroll
      for (int k=0;k<16;k++) mm = fmaxf(mm, redm[k]);
      float dt = 0.f, rs = 0.f;
      #pragma unroll
      for (int k=0;k<16;k++){
        float sc = __expf(redm[k] - mm);
        dt += redd[k]*sc;
        rs += redr[k][tid]*sc;
      }
      qsr[64+tid] = (dt > 0.f) ? rs/dt : 0.f;   // r part of q_star
    }
    __syncthreads();
  }
  // ---- final MLP
  if (tid < 64){
    float acc = b1[tid];
    for (int k=0;k<128;k++) acc += qsr[k]*W1[k*64+tid];
    yy[tid] = fmaxf(acc, 0.f);
  }
  __syncthreads();
  if (tid < 12){
    float a2 = b2[tid];
    for (int k=0;k<64;k++) a2 += yy[k]*W2[k*12+tid];
    outy[(size_t)g*12+tid] = a2;
  }
}

extern "C" void kernel_launch(void* const* d_in, const int* in_sizes, int n_in,
                              void* d_out, int out_size, void* d_ws, size_t ws_size,
                              hipStream_t stream){
  const float* x    = (const float*)d_in[0];
  const int*   ei   = (const int*)d_in[1];
  const int*   batch= (const int*)d_in[2];
  const float* W0   = (const float*)d_in[3];
  const float* b0   = (const float*)d_in[4];
  const float* Wc   = (const float*)d_in[5];
  const float* bc   = (const float*)d_in[6];
  const float* Wih  = (const float*)d_in[7];
  const float* Whh  = (const float*)d_in[8];
  const float* bih  = (const float*)d_in[9];
  const float* bhh  = (const float*)d_in[10];
  const float* W1   = (const float*)d_in[11];
  const float* b1   = (const float*)d_in[12];
  const float* W2   = (const float*)d_in[13];
  const float* b2   = (const float*)d_in[14];
  float* yout = (float*)d_out;

  const int N = in_sizes[0]/15;
  const int E = in_sizes[1]/2;
  const int B = out_size/12;
  const int NBK = (N + (1<<BKT_SHIFT) - 1) >> BKT_SHIFT;
  const int* row = ei;
  const int* col = ei + E;

  char* ws = (char*)d_ws;
  size_t off = 0;
  auto alloc = [&](size_t bytes)->void*{
    void* p = ws + off; off = (off + bytes + 255) & ~(size_t)255; return p;
  };
  int*      bgcnt   = (int*)     alloc((size_t)(NBK+1)*4);
  int*      bstart  = (int*)     alloc((size_t)(NBK+1)*4);
  int*      bcur    = (int*)     alloc((size_t)NBK*BCUR_PAD*4);
  int*      rowptr  = (int*)     alloc((size_t)(N+1)*4);
  unsigned* pairs   = (unsigned*)alloc((size_t)E*4);
  int*      csr     = (int*)     alloc((size_t)E*4);
  float*    dinv    = (float*)   alloc((size_t)N*4);
  __half*   nodef   = (__half*)  alloc((size_t)N*ND*2);
  __half*   s_a     = (__half*)  alloc((size_t)N*ND*2);
  __half*   s_b     = (__half*)  alloc((size_t)N*ND*2);
  int*      goff    = (int*)     alloc((size_t)(B+1)*4);
  float*    WcombT  = (float*)   alloc(64*256*4);
  float*    WrT     = (float*)   alloc(64*256*4);
  float*    bsum    = (float*)   alloc(256*4);
  (void)ws_size; (void)n_in;

  hipMemsetAsync(bgcnt, 0, (size_t)(NBK+1)*4, stream);

  int nstg = (E + STG_TILE - 1)/STG_TILE;
  k_bhist <<<nstg, 256, 0, stream>>>(col, bgcnt, E, NBK);
  k_bscan <<<1, 256, 0, stream>>>(bgcnt, bstart, rowptr, NBK, E, N);
  k_bcinit<<<(NBK+255)/256, 256, 0, stream>>>(bstart, bcur, NBK);
  k_stage2<<<nstg, 256, 0, stream>>>(row, col, bcur, pairs, E, NBK);
  k_place <<<NBK, 256, 0, stream>>>(pairs, bstart, rowptr, dinv, csr, N);

  k_input<<<(N+3)/4, 256, 0, stream>>>(x, W0, b0, dinv, s_a, N);
  __half* scur = s_a; __half* snxt = s_b;
  for (int s6=0; s6<6; ++s6){
    k_prop<<<(N+15)/16, 256, 0, stream>>>(scur, rowptr, csr, dinv,
                                          Wc, bc, snxt, nodef, N, (s6==5)?1:0);
    __half* t = scur; scur = snxt; snxt = t;
  }

  k_goff<<<(N+255)/256, 256, 0, stream>>>(batch, goff, N, B);
  k_wprep<<<64, 256, 0, stream>>>(Wih, Whh, bih, bhh, WcombT, WrT, bsum);
  k_s2s<<<B, 256, 0, stream>>>(nodef, goff, WcombT, WrT, bsum,
                               W1, b1, W2, b2, yout, B);
}

// Round 12
// 854.579 us; speedup vs baseline: 1.0973x; 1.0162x over previous
//
#include <hip/hip_runtime.h>
#include <hip/hip_fp16.h>
#include <math.h>

#define ND 64
constexpr int BKT_SHIFT = 9;          // 512 nodes per bucket; NBK = ceil(100k/512) = 196 <= 256
constexpr int BKT_MASK = (1 << BKT_SHIFT) - 1;
constexpr int BCUR_PAD = 16;          // ints -> 64 B per cursor
constexpr int STG_TILE = 8192;        // edges per stage block
constexpr int S2S_CAP = 192;          // nodes cached in LDS (mean ~98, +9.5 sigma; fallback if exceeded)

__device__ __forceinline__ float sigmoidf_(float x){ return 1.f/(1.f+__expf(-x)); }
__device__ __forceinline__ __half2 h2lo(uint2 v){ return *reinterpret_cast<__half2*>(&v.x); }
__device__ __forceinline__ __half2 h2hi(uint2 v){ return *reinterpret_cast<__half2*>(&v.y); }
__device__ __forceinline__ __half2 shxor_h2(__half2 h, int off){
  unsigned u = *reinterpret_cast<unsigned*>(&h);
  u = __shfl_xor(u, off, 64);
  return *reinterpret_cast<__half2*>(&u);
}

// ---------------- bucket-hierarchical CSR build ----------------
__global__ void k_bhist(const int* __restrict__ col, int* __restrict__ bgcnt,
                        int E, int NBK){
  __shared__ int lhist[512];
  int t0 = blockIdx.x * STG_TILE;
  int t1 = t0 + STG_TILE; if (t1 > E) t1 = E;
  for (int i = threadIdx.x; i < NBK; i += 256) lhist[i] = 0;
  __syncthreads();
  for (int i = t0 + threadIdx.x; i < t1; i += 256)
    atomicAdd(&lhist[col[i] >> BKT_SHIFT], 1);
  __syncthreads();
  for (int i = threadIdx.x; i < NBK; i += 256)
    if (lhist[i] > 0) atomicAdd(&bgcnt[i], lhist[i]);
}

__global__ void k_bscan(const int* __restrict__ bgcnt, int* __restrict__ bstart,
                        int* __restrict__ rowptr, int NBK, int E, int N){
  __shared__ int tmp[256];
  int t = threadIdx.x;
  int v = (t < NBK) ? bgcnt[t] : 0;
  tmp[t] = v; __syncthreads();
  for (int off=1; off<256; off<<=1){
    int u = (t>=off) ? tmp[t-off] : 0;
    __syncthreads();
    tmp[t] += u;
    __syncthreads();
  }
  if (t <= NBK) bstart[t] = (t==0) ? 0 : tmp[t-1];
  if (t == 0) rowptr[N] = E;
}

__global__ void k_bcinit(const int* __restrict__ bstart, int* __restrict__ bcur, int NBK){
  int b = blockIdx.x*blockDim.x + threadIdx.x;
  if (b < NBK) bcur[b*BCUR_PAD] = bstart[b];
}

__global__ void k_stage2(const int* __restrict__ row, const int* __restrict__ col,
                         int* __restrict__ bcur, unsigned* __restrict__ pairs,
                         int E, int NBK){
  __shared__ int lhist[512];
  __shared__ int lbase[512];
  int t0 = blockIdx.x * STG_TILE;
  int t1 = t0 + STG_TILE; if (t1 > E) t1 = E;
  for (int i = threadIdx.x; i < NBK; i += 256) lhist[i] = 0;
  __syncthreads();
  for (int i = t0 + threadIdx.x; i < t1; i += 256)
    atomicAdd(&lhist[col[i] >> BKT_SHIFT], 1);
  __syncthreads();
  for (int i = threadIdx.x; i < NBK; i += 256){
    int c = lhist[i];
    lbase[i] = (c > 0) ? atomicAdd(&bcur[i*BCUR_PAD], c) : 0;
    lhist[i] = 0;
  }
  __syncthreads();
  for (int i = t0 + threadIdx.x; i < t1; i += 256){
    int d = col[i];
    int b = d >> BKT_SHIFT;
    int pos = lbase[b] + atomicAdd(&lhist[b], 1);
    pairs[pos] = ((unsigned)row[i] << BKT_SHIFT) | (unsigned)(d & BKT_MASK);
  }
}

__global__ void k_place(const unsigned* __restrict__ pairs, const int* __restrict__ bstart,
                        int* __restrict__ rowptr, float* __restrict__ dinv,
                        int* __restrict__ csr, int N){
  __shared__ int h[1 << BKT_SHIFT];
  __shared__ int excl[1 << BKT_SHIFT];
  __shared__ int tsum[256];
  int b = blockIdx.x;
  int base = b << BKT_SHIFT;
  int nend = base + (1 << BKT_SHIFT); if (nend > N) nend = N;
  int cnt = nend - base;
  int t = threadIdx.x;
  int s = bstart[b], e = bstart[b+1];

  h[2*t] = 0; h[2*t+1] = 0;
  __syncthreads();
  for (int i = s + t; i < e; i += 256)
    atomicAdd(&h[pairs[i] & BKT_MASK], 1);
  __syncthreads();
  int a0 = h[2*t], a1 = h[2*t+1];
  tsum[t] = a0 + a1;
  __syncthreads();
  for (int off=1; off<256; off<<=1){
    int u = (t>=off) ? tsum[t-off] : 0;
    __syncthreads();
    tsum[t] += u;
    __syncthreads();
  }
  int base0 = (t==0) ? 0 : tsum[t-1];
  excl[2*t]   = base0;
  excl[2*t+1] = base0 + a0;
  __syncthreads();
  for (int c = t; c < cnt; c += 256){
    int deg = h[c];
    rowptr[base + c] = s + excl[c];
    dinv[base + c] = rsqrtf((float)(deg + 1));   // +1 = self loop
  }
  __syncthreads();
  for (int c = t; c < cnt; c += 256) h[c] = s + excl[c];
  __syncthreads();
  for (int i = s + t; i < e; i += 256){
    unsigned p = pairs[i];
    int pos = atomicAdd(&h[p & BKT_MASK], 1);
    csr[pos] = (int)(p >> BKT_SHIFT);
  }
}

// ---------------- input MLP: s0 = fp16( dinv * relu(x @ W0 + b0) ) ----------------
__global__ void k_input(const float* __restrict__ x, const float* __restrict__ W0,
                        const float* __restrict__ b0, const float* __restrict__ dinv,
                        __half* __restrict__ s, int N){
  __shared__ float w0s[15*ND];
  __shared__ float b0s[ND];
  int tid = threadIdx.x;
  for (int i=tid; i<15*ND; i+=256) w0s[i] = W0[i];
  if (tid < ND) b0s[tid] = b0[tid];
  __syncthreads();
  int node = blockIdx.x*4 + (tid>>6);
  int f = tid & 63;
  if (node < N){
    float acc = b0s[f];
    const float* xr = x + (size_t)node*15;
    #pragma unroll
    for (int k=0;k<15;k++) acc += xr[k]*w0s[k*ND+f];
    s[(size_t)node*ND+f] = __float2half_rn(dinv[node]*fmaxf(acc, 0.f));
  }
}

// ---------------- fused propagation step, packed-fp16 gather ----------------
__global__ void k_prop(const __half* __restrict__ sbuf, const int* __restrict__ rowptr,
                       const int* __restrict__ csr, const float* __restrict__ dinv,
                       const float* __restrict__ Wc, const float* __restrict__ bc,
                       __half* __restrict__ s_new, __half* __restrict__ outh,
                       int N, int wout){
  __shared__ float wcs[ND*ND];
  __shared__ float xs[16][ND];
  __shared__ float bcs[ND];
  const uint2* g8 = (const uint2*)sbuf;
  int tid = threadIdx.x;
  for (int i=tid; i<ND*ND; i+=256) wcs[i] = Wc[i];
  if (tid < ND) bcs[tid] = bc[tid];
  int nb = blockIdx.x*16;
  int wv = tid>>6, lane = tid&63;
  int grp = lane>>4, li = lane&15;

  for (int q=0; q<4; ++q){
    int node = nb + wv*4 + q;
    float val = 0.f;
    if (node < N){
      int s = rowptr[node], e = rowptr[node+1];
      __half2 z = __float2half2_rn(0.f);
      __half2 a0x=z,a0y=z, a1x=z,a1y=z, a2x=z,a2y=z, a3x=z,a3y=z;
      int i = s;
      for (; i + 16 <= e; i += 16){
        int s0 = csr[i +  0 + grp];
        int s1 = csr[i +  4 + grp];
        int s2 = csr[i +  8 + grp];
        int s3 = csr[i + 12 + grp];
        uint2 v0 = g8[(size_t)s0*16 + li];
        uint2 v1 = g8[(size_t)s1*16 + li];
        uint2 v2 = g8[(size_t)s2*16 + li];
        uint2 v3 = g8[(size_t)s3*16 + li];
        a0x = __hadd2(a0x, h2lo(v0)); a0y = __hadd2(a0y, h2hi(v0));
        a1x = __hadd2(a1x, h2lo(v1)); a1y = __hadd2(a1y, h2hi(v1));
        a2x = __hadd2(a2x, h2lo(v2)); a2y = __hadd2(a2y, h2hi(v2));
        a3x = __hadd2(a3x, h2lo(v3)); a3y = __hadd2(a3y, h2hi(v3));
      }
      for (; i + 4 <= e; i += 4){
        int s0 = csr[i + grp];
        uint2 v0 = g8[(size_t)s0*16 + li];
        a0x = __hadd2(a0x, h2lo(v0)); a0y = __hadd2(a0y, h2hi(v0));
      }
      int r = e - i;
      if (grp < r){
        int s0 = csr[i + grp];
        uint2 v0 = g8[(size_t)s0*16 + li];
        a1x = __hadd2(a1x, h2lo(v0)); a1y = __hadd2(a1y, h2hi(v0));
      }
      __half2 sxh = __hadd2(__hadd2(a0x,a1x), __hadd2(a2x,a3x));
      __half2 syh = __hadd2(__hadd2(a0y,a1y), __hadd2(a2y,a3y));
      sxh = __hadd2(sxh, shxor_h2(sxh, 16));
      syh = __hadd2(syh, shxor_h2(syh, 16));
      sxh = __hadd2(sxh, shxor_h2(sxh, 32));
      syh = __hadd2(syh, shxor_h2(syh, 32));
      uint2 sv = g8[(size_t)node*16 + li];        // self loop
      sxh = __hadd2(sxh, h2lo(sv));
      syh = __hadd2(syh, h2hi(sv));
      val = (grp==0) ? __half2float(__low2half(sxh))
          : (grp==1) ? __half2float(__high2half(sxh))
          : (grp==2) ? __half2float(__low2half(syh))
          :            __half2float(__high2half(syh));
    }
    xs[wv*4+q][4*li+grp] = val;
  }
  __syncthreads();

  int f = tid&63, nq = tid>>6;
  float acc0=0.f, acc1=0.f, acc2=0.f, acc3=0.f;
  #pragma unroll 16
  for (int k=0;k<ND;k++){
    float w = wcs[k*ND+f];
    acc0 += w*xs[nq*4+0][k];
    acc1 += w*xs[nq*4+1][k];
    acc2 += w*xs[nq*4+2][k];
    acc3 += w*xs[nq*4+3][k];
  }
  int n0 = nb + nq*4;
  float bcf = bcs[f];
  #pragma unroll
  for (int j=0; j<4; ++j){
    int node = n0 + j;
    if (node < N){
      float a = (j==0)?acc0:(j==1)?acc1:(j==2)?acc2:acc3;
      float dn = dinv[node];
      float r = fmaxf(dn*a + bcf, 0.f);
      if (wout) outh[(size_t)node*ND+f] = __float2half_rn(r);        // last step: relu-out only
      else      s_new[(size_t)node*ND+f] = __float2half_rn(dn*r);    // intermediate: pre-scaled
    }
  }
}

// ---------------- per-graph contiguous ranges (batch is sorted) ----------------
__global__ void k_goff(const int* __restrict__ batch, int* __restrict__ goff, int N, int B){
  int i = blockIdx.x*blockDim.x + threadIdx.x;
  if (i >= N) return;
  int b = batch[i];
  if (i == 0){ for (int g2=0; g2<=b; ++g2) goff[g2]=0; }
  else {
    int bp = batch[i-1];
    for (int g2=bp+1; g2<=b; ++g2) goff[g2]=i;
  }
  if (i == N-1){ for (int g2=b+1; g2<=B; ++g2) goff[g2]=N; }
}

// ---------------- LSTM weight prep ----------------
// q == h always, so gates = h@(Wih[:,:64]+Whh)^T + r@Wih[:,64:]^T + (bih+bhh).
__global__ void k_wprep(const float* __restrict__ Wih, const float* __restrict__ Whh,
                        const float* __restrict__ bih, const float* __restrict__ bhh,
                        float* __restrict__ WcombT, float* __restrict__ WrT,
                        float* __restrict__ bsum){
  int k = blockIdx.x;        // 0..63
  int j = threadIdx.x;       // 0..255
  WcombT[k*256 + j] = Wih[(size_t)j*128 + k] + Whh[(size_t)j*64 + k];
  WrT  [k*256 + j] = Wih[(size_t)j*128 + 64 + k];
  if (k == 0) bsum[j] = bih[j] + bhh[j];
}

// ---------------- fused Set2Set: one graph per block, nodef cached in LDS ----------------
// The graph's contiguous node slice (~12.5 KB fp16) is staged into dynamic LDS
// once; all 6 attention sweeps read LDS (kills the 210 MB/dispatch L2-miss
// refetch of round 10). Stride padded to 17 uint2/node to spread banks.
__global__ void k_s2s(const __half* __restrict__ nodef, const int* __restrict__ goff,
                      const float* __restrict__ WcombT, const float* __restrict__ WrT,
                      const float* __restrict__ bsum,
                      const float* __restrict__ W1, const float* __restrict__ b1,
                      const float* __restrict__ W2, const float* __restrict__ b2,
                      float* __restrict__ outy, int B){
  __shared__ float qsr[128];        // [h | r] = q_star
  __shared__ float clr[64];
  __shared__ float gat[256];
  __shared__ float redm[16], redd[16];
  __shared__ float redr[16][64];
  __shared__ float yy[64];
  extern __shared__ uint2 snode[];  // [S2S_CAP][17]
  int tid = threadIdx.x;
  int g = blockIdx.x;
  if (g >= B) return;
  if (tid < 128) qsr[tid] = 0.f;
  if (tid < 64)  clr[tid] = 0.f;
  int lane = tid&63, wv = tid>>6;
  int grp = lane>>4, li = lane&15;
  int gidx = wv*4 + grp;
  int s = goff[g], e = goff[g+1];
  int cnt = e - s;
  const uint2* nf = (const uint2*)nodef;
  bool lds_ok = (cnt <= S2S_CAP);
  if (lds_ok){
    for (int i = tid; i < cnt*16; i += 256){
      int n = i >> 4, c = i & 15;
      snode[n*17 + c] = nf[(size_t)(s+n)*16 + c];
    }
  }
  __syncthreads();

  for (int step=0; step<6; ++step){
    // ---- LSTM gates: thread = gate j; 128 MACs (combined weights), coalesced
    {
      float a0 = bsum[tid], a1 = 0.f;
      for (int k=0; k<64; k+=2){
        a0 += WcombT[(k  )*256+tid]*qsr[k  ] + WrT[(k  )*256+tid]*qsr[64+k  ];
        a1 += WcombT[(k+1)*256+tid]*qsr[k+1] + WrT[(k+1)*256+tid]*qsr[64+k+1];
      }
      gat[tid] = a0 + a1;
    }
    __syncthreads();
    if (tid < 64){
      float ig = sigmoidf_(gat[tid]);
      float fg = sigmoidf_(gat[64+tid]);
      float gv = tanhf(gat[128+tid]);
      float og = sigmoidf_(gat[192+tid]);
      float c = fg*clr[tid] + ig*gv;
      float h = og*tanhf(c);
      clr[tid] = c;
      qsr[tid] = h;                 // q part of q_star
    }
    __syncthreads();
    // ---- attention, online softmax, 16 nodes in flight, LDS-resident features
    {
      float4 q4 = *(const float4*)&qsr[4*li];
      float m = -3.0e38f, denom = 0.f;
      float r0=0.f, r1=0.f, r2=0.f, r3=0.f;
      if (lds_ok){
        for (int n = gidx; n < cnt; n += 16){
          uint2 v = snode[n*17 + li];
          float2 flo = __half22float2(h2lo(v));
          float2 fhi = __half22float2(h2hi(v));
          float p = flo.x*q4.x + flo.y*q4.y + fhi.x*q4.z + fhi.y*q4.w;
          p += __shfl_xor(p, 1, 64);
          p += __shfl_xor(p, 2, 64);
          p += __shfl_xor(p, 4, 64);
          p += __shfl_xor(p, 8, 64);
          if (p > m){
            float sc = __expf(m - p);
            denom *= sc; r0 *= sc; r1 *= sc; r2 *= sc; r3 *= sc;
            m = p;
          }
          float w = __expf(p - m);
          denom += w;
          r0 += w*flo.x; r1 += w*flo.y; r2 += w*fhi.x; r3 += w*fhi.y;
        }
      } else {
        for (int n = s + gidx; n < e; n += 16){
          uint2 v = nf[(size_t)n*16 + li];
          float2 flo = __half22float2(h2lo(v));
          float2 fhi = __half22float2(h2hi(v));
          float p = flo.x*q4.x + flo.y*q4.y + fhi.x*q4.z + fhi.y*q4.w;
          p += __shfl_xor(p, 1, 64);
          p += __shfl_xor(p, 2, 64);
          p += __shfl_xor(p, 4, 64);
          p += __shfl_xor(p, 8, 64);
          if (p > m){
            float sc = __expf(m - p);
            denom *= sc; r0 *= sc; r1 *= sc; r2 *= sc; r3 *= sc;
            m = p;
          }
          float w = __expf(p - m);
          denom += w;
          r0 += w*flo.x; r1 += w*flo.y; r2 += w*fhi.x; r3 += w*fhi.y;
        }
      }
      if (li == 0){ redm[gidx] = m; redd[gidx] = denom; }
      redr[gidx][4*li+0] = r0;
      redr[gidx][4*li+1] = r1;
      redr[gidx][4*li+2] = r2;
      redr[gidx][4*li+3] = r3;
    }
    __syncthreads();
    if (tid < 64){
      float mm = -3.0e38f;
      #pragma unroll
      for (int k=0;k<16;k++) mm = fmaxf(mm, redm[k]);
      float dt = 0.f, rs = 0.f;
      #pragma unroll
      for (int k=0;k<16;k++){
        float sc = __expf(redm[k] - mm);
        dt += redd[k]*sc;
        rs += redr[k][tid]*sc;
      }
      qsr[64+tid] = (dt > 0.f) ? rs/dt : 0.f;   // r part of q_star
    }
    __syncthreads();
  }
  // ---- final MLP
  if (tid < 64){
    float acc = b1[tid];
    for (int k=0;k<128;k++) acc += qsr[k]*W1[k*64+tid];
    yy[tid] = fmaxf(acc, 0.f);
  }
  __syncthreads();
  if (tid < 12){
    float a2 = b2[tid];
    for (int k=0;k<64;k++) a2 += yy[k]*W2[k*12+tid];
    outy[(size_t)g*12+tid] = a2;
  }
}

extern "C" void kernel_launch(void* const* d_in, const int* in_sizes, int n_in,
                              void* d_out, int out_size, void* d_ws, size_t ws_size,
                              hipStream_t stream){
  const float* x    = (const float*)d_in[0];
  const int*   ei   = (const int*)d_in[1];
  const int*   batch= (const int*)d_in[2];
  const float* W0   = (const float*)d_in[3];
  const float* b0   = (const float*)d_in[4];
  const float* Wc   = (const float*)d_in[5];
  const float* bc   = (const float*)d_in[6];
  const float* Wih  = (const float*)d_in[7];
  const float* Whh  = (const float*)d_in[8];
  const float* bih  = (const float*)d_in[9];
  const float* bhh  = (const float*)d_in[10];
  const float* W1   = (const float*)d_in[11];
  const float* b1   = (const float*)d_in[12];
  const float* W2   = (const float*)d_in[13];
  const float* b2   = (const float*)d_in[14];
  float* yout = (float*)d_out;

  const int N = in_sizes[0]/15;
  const int E = in_sizes[1]/2;
  const int B = out_size/12;
  const int NBK = (N + (1<<BKT_SHIFT) - 1) >> BKT_SHIFT;
  const int* row = ei;
  const int* col = ei + E;

  char* ws = (char*)d_ws;
  size_t off = 0;
  auto alloc = [&](size_t bytes)->void*{
    void* p = ws + off; off = (off + bytes + 255) & ~(size_t)255; return p;
  };
  int*      bgcnt   = (int*)     alloc((size_t)(NBK+1)*4);
  int*      bstart  = (int*)     alloc((size_t)(NBK+1)*4);
  int*      bcur    = (int*)     alloc((size_t)NBK*BCUR_PAD*4);
  int*      rowptr  = (int*)     alloc((size_t)(N+1)*4);
  unsigned* pairs   = (unsigned*)alloc((size_t)E*4);
  int*      csr     = (int*)     alloc((size_t)E*4);
  float*    dinv    = (float*)   alloc((size_t)N*4);
  __half*   nodef   = (__half*)  alloc((size_t)N*ND*2);
  __half*   s_a     = (__half*)  alloc((size_t)N*ND*2);
  __half*   s_b     = (__half*)  alloc((size_t)N*ND*2);
  int*      goff    = (int*)     alloc((size_t)(B+1)*4);
  float*    WcombT  = (float*)   alloc(64*256*4);
  float*    WrT     = (float*)   alloc(64*256*4);
  float*    bsum    = (float*)   alloc(256*4);
  (void)ws_size; (void)n_in;

  hipMemsetAsync(bgcnt, 0, (size_t)(NBK+1)*4, stream);

  int nstg = (E + STG_TILE - 1)/STG_TILE;
  k_bhist <<<nstg, 256, 0, stream>>>(col, bgcnt, E, NBK);
  k_bscan <<<1, 256, 0, stream>>>(bgcnt, bstart, rowptr, NBK, E, N);
  k_bcinit<<<(NBK+255)/256, 256, 0, stream>>>(bstart, bcur, NBK);
  k_stage2<<<nstg, 256, 0, stream>>>(row, col, bcur, pairs, E, NBK);
  k_place <<<NBK, 256, 0, stream>>>(pairs, bstart, rowptr, dinv, csr, N);

  k_input<<<(N+3)/4, 256, 0, stream>>>(x, W0, b0, dinv, s_a, N);
  __half* scur = s_a; __half* snxt = s_b;
  for (int s6=0; s6<6; ++s6){
    k_prop<<<(N+15)/16, 256, 0, stream>>>(scur, rowptr, csr, dinv,
                                          Wc, bc, snxt, nodef, N, (s6==5)?1:0);
    __half* t = scur; scur = snxt; snxt = t;
  }

  k_goff<<<(N+255)/256, 256, 0, stream>>>(batch, goff, N, B);
  k_wprep<<<64, 256, 0, stream>>>(Wih, Whh, bih, bhh, WcombT, WrT, bsum);
  size_t s2s_lds = (size_t)S2S_CAP*17*sizeof(uint2);   // 26112 B dynamic
  k_s2s<<<B, 256, s2s_lds, stream>>>(nodef, goff, WcombT, WrT, bsum,
                                     W1, b1, W2, b2, yout, B);
}

// Round 13
// 839.052 us; speedup vs baseline: 1.1176x; 1.0185x over previous
//
#include <hip/hip_runtime.h>
#include <hip/hip_fp16.h>
#include <math.h>

#define ND 64
constexpr int BKT_SHIFT = 9;          // 512 nodes per bucket; NBK = ceil(100k/512) = 196 <= 256
constexpr int BKT_MASK = (1 << BKT_SHIFT) - 1;
constexpr int BCUR_PAD = 16;          // ints -> 64 B per cursor
constexpr int STG_TILE = 8192;        // edges per stage block
constexpr int S2S_CAP = 144;          // nodes cached in LDS per graph (mean ~98, +4.7 sigma; global fallback)

__device__ __forceinline__ float sigmoidf_(float x){ return 1.f/(1.f+__expf(-x)); }
__device__ __forceinline__ __half2 h2lo(uint2 v){ return *reinterpret_cast<__half2*>(&v.x); }
__device__ __forceinline__ __half2 h2hi(uint2 v){ return *reinterpret_cast<__half2*>(&v.y); }
__device__ __forceinline__ __half2 shxor_h2(__half2 h, int off){
  unsigned u = *reinterpret_cast<unsigned*>(&h);
  u = __shfl_xor(u, off, 64);
  return *reinterpret_cast<__half2*>(&u);
}

// ---------------- bucket-hierarchical CSR build ----------------
__global__ void k_bhist(const int* __restrict__ col, int* __restrict__ bgcnt,
                        int E, int NBK){
  __shared__ int lhist[512];
  int t0 = blockIdx.x * STG_TILE;
  int t1 = t0 + STG_TILE; if (t1 > E) t1 = E;
  for (int i = threadIdx.x; i < NBK; i += 256) lhist[i] = 0;
  __syncthreads();
  for (int i = t0 + threadIdx.x; i < t1; i += 256)
    atomicAdd(&lhist[col[i] >> BKT_SHIFT], 1);
  __syncthreads();
  for (int i = threadIdx.x; i < NBK; i += 256)
    if (lhist[i] > 0) atomicAdd(&bgcnt[i], lhist[i]);
}

__global__ void k_bscan(const int* __restrict__ bgcnt, int* __restrict__ bstart,
                        int* __restrict__ rowptr, int NBK, int E, int N){
  __shared__ int tmp[256];
  int t = threadIdx.x;
  int v = (t < NBK) ? bgcnt[t] : 0;
  tmp[t] = v; __syncthreads();
  for (int off=1; off<256; off<<=1){
    int u = (t>=off) ? tmp[t-off] : 0;
    __syncthreads();
    tmp[t] += u;
    __syncthreads();
  }
  if (t <= NBK) bstart[t] = (t==0) ? 0 : tmp[t-1];
  if (t == 0) rowptr[N] = E;
}

__global__ void k_bcinit(const int* __restrict__ bstart, int* __restrict__ bcur, int NBK){
  int b = blockIdx.x*blockDim.x + threadIdx.x;
  if (b < NBK) bcur[b*BCUR_PAD] = bstart[b];
}

__global__ void k_stage2(const int* __restrict__ row, const int* __restrict__ col,
                         int* __restrict__ bcur, unsigned* __restrict__ pairs,
                         int E, int NBK){
  __shared__ int lhist[512];
  __shared__ int lbase[512];
  int t0 = blockIdx.x * STG_TILE;
  int t1 = t0 + STG_TILE; if (t1 > E) t1 = E;
  for (int i = threadIdx.x; i < NBK; i += 256) lhist[i] = 0;
  __syncthreads();
  for (int i = t0 + threadIdx.x; i < t1; i += 256)
    atomicAdd(&lhist[col[i] >> BKT_SHIFT], 1);
  __syncthreads();
  for (int i = threadIdx.x; i < NBK; i += 256){
    int c = lhist[i];
    lbase[i] = (c > 0) ? atomicAdd(&bcur[i*BCUR_PAD], c) : 0;
    lhist[i] = 0;
  }
  __syncthreads();
  for (int i = t0 + threadIdx.x; i < t1; i += 256){
    int d = col[i];
    int b = d >> BKT_SHIFT;
    int pos = lbase[b] + atomicAdd(&lhist[b], 1);
    pairs[pos] = ((unsigned)row[i] << BKT_SHIFT) | (unsigned)(d & BKT_MASK);
  }
}

__global__ void k_place(const unsigned* __restrict__ pairs, const int* __restrict__ bstart,
                        int* __restrict__ rowptr, float* __restrict__ dinv,
                        int* __restrict__ csr, int N){
  __shared__ int h[1 << BKT_SHIFT];
  __shared__ int excl[1 << BKT_SHIFT];
  __shared__ int tsum[256];
  int b = blockIdx.x;
  int base = b << BKT_SHIFT;
  int nend = base + (1 << BKT_SHIFT); if (nend > N) nend = N;
  int cnt = nend - base;
  int t = threadIdx.x;
  int s = bstart[b], e = bstart[b+1];

  h[2*t] = 0; h[2*t+1] = 0;
  __syncthreads();
  for (int i = s + t; i < e; i += 256)
    atomicAdd(&h[pairs[i] & BKT_MASK], 1);
  __syncthreads();
  int a0 = h[2*t], a1 = h[2*t+1];
  tsum[t] = a0 + a1;
  __syncthreads();
  for (int off=1; off<256; off<<=1){
    int u = (t>=off) ? tsum[t-off] : 0;
    __syncthreads();
    tsum[t] += u;
    __syncthreads();
  }
  int base0 = (t==0) ? 0 : tsum[t-1];
  excl[2*t]   = base0;
  excl[2*t+1] = base0 + a0;
  __syncthreads();
  for (int c = t; c < cnt; c += 256){
    int deg = h[c];
    rowptr[base + c] = s + excl[c];
    dinv[base + c] = rsqrtf((float)(deg + 1));   // +1 = self loop
  }
  __syncthreads();
  for (int c = t; c < cnt; c += 256) h[c] = s + excl[c];
  __syncthreads();
  for (int i = s + t; i < e; i += 256){
    unsigned p = pairs[i];
    int pos = atomicAdd(&h[p & BKT_MASK], 1);
    csr[pos] = (int)(p >> BKT_SHIFT);
  }
}

// ---------------- input MLP: s0 = fp16( dinv * relu(x @ W0 + b0) ) ----------------
__global__ void k_input(const float* __restrict__ x, const float* __restrict__ W0,
                        const float* __restrict__ b0, const float* __restrict__ dinv,
                        __half* __restrict__ s, int N){
  __shared__ float w0s[15*ND];
  __shared__ float b0s[ND];
  int tid = threadIdx.x;
  for (int i=tid; i<15*ND; i+=256) w0s[i] = W0[i];
  if (tid < ND) b0s[tid] = b0[tid];
  __syncthreads();
  int node = blockIdx.x*4 + (tid>>6);
  int f = tid & 63;
  if (node < N){
    float acc = b0s[f];
    const float* xr = x + (size_t)node*15;
    #pragma unroll
    for (int k=0;k<15;k++) acc += xr[k]*w0s[k*ND+f];
    s[(size_t)node*ND+f] = __float2half_rn(dinv[node]*fmaxf(acc, 0.f));
  }
}

// ---------------- fused propagation step, packed-fp16 gather ----------------
__global__ void k_prop(const __half* __restrict__ sbuf, const int* __restrict__ rowptr,
                       const int* __restrict__ csr, const float* __restrict__ dinv,
                       const float* __restrict__ Wc, const float* __restrict__ bc,
                       __half* __restrict__ s_new, __half* __restrict__ outh,
                       int N, int wout){
  __shared__ float wcs[ND*ND];
  __shared__ float xs[16][ND];
  __shared__ float bcs[ND];
  const uint2* g8 = (const uint2*)sbuf;
  int tid = threadIdx.x;
  for (int i=tid; i<ND*ND; i+=256) wcs[i] = Wc[i];
  if (tid < ND) bcs[tid] = bc[tid];
  int nb = blockIdx.x*16;
  int wv = tid>>6, lane = tid&63;
  int grp = lane>>4, li = lane&15;

  for (int q=0; q<4; ++q){
    int node = nb + wv*4 + q;
    float val = 0.f;
    if (node < N){
      int s = rowptr[node], e = rowptr[node+1];
      __half2 z = __float2half2_rn(0.f);
      __half2 a0x=z,a0y=z, a1x=z,a1y=z, a2x=z,a2y=z, a3x=z,a3y=z;
      int i = s;
      for (; i + 16 <= e; i += 16){
        int s0 = csr[i +  0 + grp];
        int s1 = csr[i +  4 + grp];
        int s2 = csr[i +  8 + grp];
        int s3 = csr[i + 12 + grp];
        uint2 v0 = g8[(size_t)s0*16 + li];
        uint2 v1 = g8[(size_t)s1*16 + li];
        uint2 v2 = g8[(size_t)s2*16 + li];
        uint2 v3 = g8[(size_t)s3*16 + li];
        a0x = __hadd2(a0x, h2lo(v0)); a0y = __hadd2(a0y, h2hi(v0));
        a1x = __hadd2(a1x, h2lo(v1)); a1y = __hadd2(a1y, h2hi(v1));
        a2x = __hadd2(a2x, h2lo(v2)); a2y = __hadd2(a2y, h2hi(v2));
        a3x = __hadd2(a3x, h2lo(v3)); a3y = __hadd2(a3y, h2hi(v3));
      }
      for (; i + 4 <= e; i += 4){
        int s0 = csr[i + grp];
        uint2 v0 = g8[(size_t)s0*16 + li];
        a0x = __hadd2(a0x, h2lo(v0)); a0y = __hadd2(a0y, h2hi(v0));
      }
      int r = e - i;
      if (grp < r){
        int s0 = csr[i + grp];
        uint2 v0 = g8[(size_t)s0*16 + li];
        a1x = __hadd2(a1x, h2lo(v0)); a1y = __hadd2(a1y, h2hi(v0));
      }
      __half2 sxh = __hadd2(__hadd2(a0x,a1x), __hadd2(a2x,a3x));
      __half2 syh = __hadd2(__hadd2(a0y,a1y), __hadd2(a2y,a3y));
      sxh = __hadd2(sxh, shxor_h2(sxh, 16));
      syh = __hadd2(syh, shxor_h2(syh, 16));
      sxh = __hadd2(sxh, shxor_h2(sxh, 32));
      syh = __hadd2(syh, shxor_h2(syh, 32));
      uint2 sv = g8[(size_t)node*16 + li];        // self loop
      sxh = __hadd2(sxh, h2lo(sv));
      syh = __hadd2(syh, h2hi(sv));
      val = (grp==0) ? __half2float(__low2half(sxh))
          : (grp==1) ? __half2float(__high2half(sxh))
          : (grp==2) ? __half2float(__low2half(syh))
          :            __half2float(__high2half(syh));
    }
    xs[wv*4+q][4*li+grp] = val;
  }
  __syncthreads();

  int f = tid&63, nq = tid>>6;
  float acc0=0.f, acc1=0.f, acc2=0.f, acc3=0.f;
  #pragma unroll 16
  for (int k=0;k<ND;k++){
    float w = wcs[k*ND+f];
    acc0 += w*xs[nq*4+0][k];
    acc1 += w*xs[nq*4+1][k];
    acc2 += w*xs[nq*4+2][k];
    acc3 += w*xs[nq*4+3][k];
  }
  int n0 = nb + nq*4;
  float bcf = bcs[f];
  #pragma unroll
  for (int j=0; j<4; ++j){
    int node = n0 + j;
    if (node < N){
      float a = (j==0)?acc0:(j==1)?acc1:(j==2)?acc2:acc3;
      float dn = dinv[node];
      float r = fmaxf(dn*a + bcf, 0.f);
      if (wout) outh[(size_t)node*ND+f] = __float2half_rn(r);        // last step: relu-out only
      else      s_new[(size_t)node*ND+f] = __float2half_rn(dn*r);    // intermediate: pre-scaled
    }
  }
}

// ---------------- per-graph contiguous ranges (batch is sorted) ----------------
__global__ void k_goff(const int* __restrict__ batch, int* __restrict__ goff, int N, int B){
  int i = blockIdx.x*blockDim.x + threadIdx.x;
  if (i >= N) return;
  int b = batch[i];
  if (i == 0){ for (int g2=0; g2<=b; ++g2) goff[g2]=0; }
  else {
    int bp = batch[i-1];
    for (int g2=bp+1; g2<=b; ++g2) goff[g2]=i;
  }
  if (i == N-1){ for (int g2=b+1; g2<=B; ++g2) goff[g2]=N; }
}

// ---------------- LSTM weight prep: packed fp16, [k2][j] layout ----------------
// q == h always, so gates = h@(Wih[:,:64]+Whh)^T + r@Wih[:,64:]^T + (bih+bhh).
__global__ void k_wprep(const float* __restrict__ Wih, const float* __restrict__ Whh,
                        const float* __restrict__ bih, const float* __restrict__ bhh,
                        unsigned* __restrict__ WC2, unsigned* __restrict__ WR2,
                        float* __restrict__ bsum){
  int k2 = blockIdx.x;       // 0..31
  int j  = threadIdx.x;      // 0..255
  int k = 2*k2;
  float c0 = Wih[(size_t)j*128 + k]     + Whh[(size_t)j*64 + k];
  float c1 = Wih[(size_t)j*128 + k + 1] + Whh[(size_t)j*64 + k + 1];
  float r0 = Wih[(size_t)j*128 + 64 + k];
  float r1 = Wih[(size_t)j*128 + 64 + k + 1];
  __half2 hc = __halves2half2(__float2half_rn(c0), __float2half_rn(c1));
  __half2 hr = __halves2half2(__float2half_rn(r0), __float2half_rn(r1));
  WC2[k2*256 + j] = *reinterpret_cast<unsigned*>(&hc);
  WR2[k2*256 + j] = *reinterpret_cast<unsigned*>(&hr);
  if (k2 == 0) bsum[j] = bih[j] + bhh[j];
}

// ---------------- fused Set2Set: 4 graphs per block, weights + nodes in LDS ----------------
// Weights (64 KB fp16) staged once per block, amortized over 4 graphs x 6 steps
// (kills the per-step 128 KB L2 weight re-read that bound round 12's k_s2s).
// Wave wv owns graph g0+wv for attention (4 groups x 16 lanes, online softmax).
// Gate GEMV: thread = gate j, 4 graph-accumulators (4x weight amortization).
__global__ void k_s2s(const __half* __restrict__ nodef, const int* __restrict__ goff,
                      const unsigned* __restrict__ WC2g, const unsigned* __restrict__ WR2g,
                      const float* __restrict__ bsum,
                      const float* __restrict__ W1, const float* __restrict__ b1,
                      const float* __restrict__ W2, const float* __restrict__ b2,
                      float* __restrict__ outy, int B){
  __shared__ unsigned lwc[32*256];          // 32 KB fp16x2 combined weights
  __shared__ unsigned lwr[32*256];          // 32 KB fp16x2 r-weights
  __shared__ float qsr[4][128];             // [h | r] per graph
  __shared__ float clr[4][64];
  __shared__ float gat[4][256];
  __shared__ float redm[4][4], redd[4][4];
  __shared__ float redr[4][4][64];
  __shared__ float yy[4][64];
  __shared__ uint2 snode[4][S2S_CAP*17];    // 78336 B node cache (17-pad banks)

  int tid = threadIdx.x;
  int g0 = blockIdx.x*4;
  int lane = tid&63, wv = tid>>6;
  int grp = lane>>4, li = lane&15;

  for (int i=tid; i<32*256; i+=256){ lwc[i] = WC2g[i]; lwr[i] = WR2g[i]; }
  for (int i=tid; i<4*128; i+=256) qsr[i>>7][i&127] = 0.f;
  if (tid < 256){ clr[tid>>6][tid&63] = 0.f; }

  int mygraph = g0 + wv;
  int s = 0, cnt = 0;
  const uint2* nf = (const uint2*)nodef;
  bool lds_ok = false;
  if (mygraph < B){
    s = goff[mygraph];
    cnt = goff[mygraph+1] - s;
    lds_ok = (cnt <= S2S_CAP);
    if (lds_ok){
      for (int i = lane; i < cnt*16; i += 64){
        int n = i >> 4, c = i & 15;
        snode[wv][n*17 + c] = nf[(size_t)(s+n)*16 + c];
      }
    }
  }
  float bsv = bsum[tid];
  __syncthreads();

  for (int step=0; step<6; ++step){
    // ---- LSTM gates: thread = gate j, 4 graphs at once, weights from LDS
    {
      float a0=bsv, a1=bsv, a2=bsv, a3=bsv;
      for (int k2=0; k2<32; ++k2){
        unsigned uc = lwc[k2*256 + tid];
        unsigned ur = lwr[k2*256 + tid];
        float2 wc = __half22float2(*reinterpret_cast<__half2*>(&uc));
        float2 wr = __half22float2(*reinterpret_cast<__half2*>(&ur));
        float2 h0 = *(const float2*)&qsr[0][2*k2];
        float2 h1 = *(const float2*)&qsr[1][2*k2];
        float2 h2 = *(const float2*)&qsr[2][2*k2];
        float2 h3 = *(const float2*)&qsr[3][2*k2];
        float2 r0 = *(const float2*)&qsr[0][64+2*k2];
        float2 r1 = *(const float2*)&qsr[1][64+2*k2];
        float2 r2 = *(const float2*)&qsr[2][64+2*k2];
        float2 r3 = *(const float2*)&qsr[3][64+2*k2];
        a0 += wc.x*h0.x + wc.y*h0.y + wr.x*r0.x + wr.y*r0.y;
        a1 += wc.x*h1.x + wc.y*h1.y + wr.x*r1.x + wr.y*r1.y;
        a2 += wc.x*h2.x + wc.y*h2.y + wr.x*r2.x + wr.y*r2.y;
        a3 += wc.x*h3.x + wc.y*h3.y + wr.x*r3.x + wr.y*r3.y;
      }
      gat[0][tid]=a0; gat[1][tid]=a1; gat[2][tid]=a2; gat[3][tid]=a3;
    }
    __syncthreads();
    {   // pointwise: thread = (graph, d)
      int gg = tid>>6, d = tid&63;
      float ig = sigmoidf_(gat[gg][d]);
      float fg = sigmoidf_(gat[gg][64+d]);
      float gv = tanhf(gat[gg][128+d]);
      float og = sigmoidf_(gat[gg][192+d]);
      float c = fg*clr[gg][d] + ig*gv;
      float h = og*tanhf(c);
      clr[gg][d] = c;
      qsr[gg][d] = h;
    }
    __syncthreads();
    // ---- attention: wave wv -> graph g0+wv; 4 groups x 16 lanes, online softmax
    {
      float4 q4 = *(const float4*)&qsr[wv][4*li];
      float m = -3.0e38f, denom = 0.f;
      float r0=0.f, r1=0.f, r2=0.f, r3=0.f;
      if (lds_ok){
        for (int n = grp; n < cnt; n += 4){
          uint2 v = snode[wv][n*17 + li];
          float2 flo = __half22float2(h2lo(v));
          float2 fhi = __half22float2(h2hi(v));
          float p = flo.x*q4.x + flo.y*q4.y + fhi.x*q4.z + fhi.y*q4.w;
          p += __shfl_xor(p, 1, 64);
          p += __shfl_xor(p, 2, 64);
          p += __shfl_xor(p, 4, 64);
          p += __shfl_xor(p, 8, 64);
          if (p > m){
            float sc = __expf(m - p);
            denom *= sc; r0 *= sc; r1 *= sc; r2 *= sc; r3 *= sc;
            m = p;
          }
          float w = __expf(p - m);
          denom += w;
          r0 += w*flo.x; r1 += w*flo.y; r2 += w*fhi.x; r3 += w*fhi.y;
        }
      } else if (mygraph < B){
        for (int n = grp; n < cnt; n += 4){
          uint2 v = nf[(size_t)(s+n)*16 + li];
          float2 flo = __half22float2(h2lo(v));
          float2 fhi = __half22float2(h2hi(v));
          float p = flo.x*q4.x + flo.y*q4.y + fhi.x*q4.z + fhi.y*q4.w;
          p += __shfl_xor(p, 1, 64);
          p += __shfl_xor(p, 2, 64);
          p += __shfl_xor(p, 4, 64);
          p += __shfl_xor(p, 8, 64);
          if (p > m){
            float sc = __expf(m - p);
            denom *= sc; r0 *= sc; r1 *= sc; r2 *= sc; r3 *= sc;
            m = p;
          }
          float w = __expf(p - m);
          denom += w;
          r0 += w*flo.x; r1 += w*flo.y; r2 += w*fhi.x; r3 += w*fhi.y;
        }
      }
      if (li == 0){ redm[wv][grp] = m; redd[wv][grp] = denom; }
      redr[wv][grp][4*li+0] = r0;
      redr[wv][grp][4*li+1] = r1;
      redr[wv][grp][4*li+2] = r2;
      redr[wv][grp][4*li+3] = r3;
    }
    __syncthreads();
    {   // merge 4 groups per graph: thread = (graph, d)
      int gg = tid>>6, d = tid&63;
      float m0=redm[gg][0], m1=redm[gg][1], m2=redm[gg][2], m3=redm[gg][3];
      float mm = fmaxf(fmaxf(m0,m1), fmaxf(m2,m3));
      float s0=__expf(m0-mm), s1=__expf(m1-mm), s2=__expf(m2-mm), s3=__expf(m3-mm);
      float dt = redd[gg][0]*s0 + redd[gg][1]*s1 + redd[gg][2]*s2 + redd[gg][3]*s3;
      float rs = redr[gg][0][d]*s0 + redr[gg][1][d]*s1 + redr[gg][2][d]*s2 + redr[gg][3][d]*s3;
      qsr[gg][64+d] = (dt > 0.f) ? rs/dt : 0.f;
    }
    __syncthreads();
  }
  // ---- final MLP: thread = (graph, f)
  {
    int gg = tid>>6, f = tid&63;
    float acc = b1[f];
    for (int k=0;k<128;k++) acc += qsr[gg][k]*W1[k*64+f];
    yy[gg][f] = fmaxf(acc, 0.f);
  }
  __syncthreads();
  if (tid < 48){
    int gg = tid/12, o = tid%12;
    if (g0+gg < B){
      float a2 = b2[o];
      for (int k=0;k<64;k++) a2 += yy[gg][k]*W2[k*12+o];
      outy[(size_t)(g0+gg)*12+o] = a2;
    }
  }
}

extern "C" void kernel_launch(void* const* d_in, const int* in_sizes, int n_in,
                              void* d_out, int out_size, void* d_ws, size_t ws_size,
                              hipStream_t stream){
  const float* x    = (const float*)d_in[0];
  const int*   ei   = (const int*)d_in[1];
  const int*   batch= (const int*)d_in[2];
  const float* W0   = (const float*)d_in[3];
  const float* b0   = (const float*)d_in[4];
  const float* Wc   = (const float*)d_in[5];
  const float* bc   = (const float*)d_in[6];
  const float* Wih  = (const float*)d_in[7];
  const float* Whh  = (const float*)d_in[8];
  const float* bih  = (const float*)d_in[9];
  const float* bhh  = (const float*)d_in[10];
  const float* W1   = (const float*)d_in[11];
  const float* b1   = (const float*)d_in[12];
  const float* W2   = (const float*)d_in[13];
  const float* b2   = (const float*)d_in[14];
  float* yout = (float*)d_out;

  const int N = in_sizes[0]/15;
  const int E = in_sizes[1]/2;
  const int B = out_size/12;
  const int NBK = (N + (1<<BKT_SHIFT) - 1) >> BKT_SHIFT;
  const int* row = ei;
  const int* col = ei + E;

  char* ws = (char*)d_ws;
  size_t off = 0;
  auto alloc = [&](size_t bytes)->void*{
    void* p = ws + off; off = (off + bytes + 255) & ~(size_t)255; return p;
  };
  int*      bgcnt   = (int*)     alloc((size_t)(NBK+1)*4);
  int*      bstart  = (int*)     alloc((size_t)(NBK+1)*4);
  int*      bcur    = (int*)     alloc((size_t)NBK*BCUR_PAD*4);
  int*      rowptr  = (int*)     alloc((size_t)(N+1)*4);
  unsigned* pairs   = (unsigned*)alloc((size_t)E*4);
  int*      csr     = (int*)     alloc((size_t)E*4);
  float*    dinv    = (float*)   alloc((size_t)N*4);
  __half*   nodef   = (__half*)  alloc((size_t)N*ND*2);
  __half*   s_a     = (__half*)  alloc((size_t)N*ND*2);
  __half*   s_b     = (__half*)  alloc((size_t)N*ND*2);
  int*      goff    = (int*)     alloc((size_t)(B+1)*4);
  unsigned* WC2     = (unsigned*)alloc(32*256*4);
  unsigned* WR2     = (unsigned*)alloc(32*256*4);
  float*    bsum    = (float*)   alloc(256*4);
  (void)ws_size; (void)n_in;

  hipMemsetAsync(bgcnt, 0, (size_t)(NBK+1)*4, stream);

  int nstg = (E + STG_TILE - 1)/STG_TILE;
  k_bhist <<<nstg, 256, 0, stream>>>(col, bgcnt, E, NBK);
  k_bscan <<<1, 256, 0, stream>>>(bgcnt, bstart, rowptr, NBK, E, N);
  k_bcinit<<<(NBK+255)/256, 256, 0, stream>>>(bstart, bcur, NBK);
  k_stage2<<<nstg, 256, 0, stream>>>(row, col, bcur, pairs, E, NBK);
  k_place <<<NBK, 256, 0, stream>>>(pairs, bstart, rowptr, dinv, csr, N);

  k_input<<<(N+3)/4, 256, 0, stream>>>(x, W0, b0, dinv, s_a, N);
  __half* scur = s_a; __half* snxt = s_b;
  for (int s6=0; s6<6; ++s6){
    k_prop<<<(N+15)/16, 256, 0, stream>>>(scur, rowptr, csr, dinv,
                                          Wc, bc, snxt, nodef, N, (s6==5)?1:0);
    __half* t = scur; scur = snxt; snxt = t;
  }

  k_goff<<<(N+255)/256, 256, 0, stream>>>(batch, goff, N, B);
  k_wprep<<<32, 256, 0, stream>>>(Wih, Whh, bih, bhh, WC2, WR2, bsum);
  k_s2s<<<(B+3)/4, 256, 0, stream>>>(nodef, goff, WC2, WR2, bsum,
                                     W1, b1, W2, b2, yout, B);
}